// Round 5
// baseline (532.143 us; speedup 1.0000x reference)
//
#include <hip/hip_runtime.h>
#include <stdint.h>

#define BB   16
#define NN   65536
#define FF   32
#define KSEL 16384
#define EPSF 1e-10f
#define NBIN 512            // 9-bit first radix: sign + 8 exp bits (one binade per bin)
#define NSHARD 8
#define CAP_SHARD 1536
#define CAP_COL (NSHARD*CAP_SHARD)   // 12288 candidates per column

typedef float f4v __attribute__((ext_vector_type(4)));

// ---- workspace layout (uint32 element offsets), ~51.4 MB ----
#define WS_MIN   0                      // 1 (memset 0xFF)
#define WS_PREF  8                      // [512] 9-bit bucket per column
#define WS_REM   520                    // [512] remaining rank within bucket
#define WS_T     1032                   // u64[512] exact threshold (byte off 4128, 8-aligned)
#define WS_EQC   2056                   // [512][8] shard counters (memset 0)
#define WS_HIST  6152                   // [512][512] global hist (memset 0)
#define WS_CAND  268296                 // u64[512][12288] (byte off 1073184, 8-aligned)

__device__ __forceinline__ uint32_t fkey(float s) {
    uint32_t u = __float_as_uint(s);
    return (u & 0x80000000u) ? ~u : (u | 0x80000000u);
}

// ---- 1) fused min(|x|) + 9-bit hist on raw x keys; LDS hist -> global atomics ----
__global__ __launch_bounds__(512) void khist(const float* __restrict__ xf, uint32_t* __restrict__ ws) {
    __shared__ uint32_t lh[NBIN * 33];    // [bin][f], stride 33
    __shared__ uint32_t rmin[512];
    const int b = blockIdx.x >> 5;
    const int s = blockIdx.x & 31;
    const int tid = threadIdx.x;
    for (int i = tid; i < NBIN * 33; i += 512) lh[i] = 0;
    __syncthreads();
    const float4* x4 = (const float4*)xf + (size_t)b * (NN * FF / 4) + (size_t)s * 16384;
    uint32_t mreg = 0xFFFFFFFFu;
#pragma unroll
    for (int c = 0; c < 4; ++c) {
        float4 v[8];
#pragma unroll
        for (int k = 0; k < 8; ++k) v[k] = x4[c * 4096 + k * 512 + tid];
#pragma unroll
        for (int k = 0; k < 8; ++k) {
            const int e = c * 4096 + k * 512 + tid;
            const int fb = (e & 7) * 4;
            float vv[4] = {v[k].x, v[k].y, v[k].z, v[k].w};
#pragma unroll
            for (int j = 0; j < 4; ++j) {
                uint32_t u = __float_as_uint(vv[j]);
                uint32_t a = u & 0x7FFFFFFFu;
                mreg = a < mreg ? a : mreg;
                uint32_t key = (u & 0x80000000u) ? ~u : (u | 0x80000000u);
                atomicAdd(&lh[(key >> 23) * 33 + fb + j], 1u);
            }
        }
    }
    rmin[tid] = mreg;
    __syncthreads();
    for (int off = 256; off > 0; off >>= 1) {
        if (tid < off) { uint32_t o = rmin[tid + off]; if (o < rmin[tid]) rmin[tid] = o; }
        __syncthreads();
    }
    if (tid == 0) atomicMin(&ws[WS_MIN], rmin[0]);
    for (int k = tid; k < NBIN * 32; k += 512) {
        const int bin = k >> 5, f = k & 31;
        uint32_t val = lh[bin * 33 + f];
        if (val) atomicAdd(&ws[WS_HIST + bin * 512 + b * 32 + f], val);
    }
}

// ---- 2) per-column: bucket containing rank-K + remaining rank (branchless scan) ----
__global__ __launch_bounds__(512) void kresolve(uint32_t* __restrict__ ws) {
    const int col = threadIdx.x;
    const uint32_t* hist = ws + WS_HIST;
    uint32_t r = KSEL, cum = 0, v = 0, rfin = 1;
    bool found = false;
    for (int bin = NBIN - 1; bin >= 0; --bin) {
        uint32_t h = hist[bin * 512 + col];
        uint32_t nc = cum + h;
        if (!found && nc >= r) { v = (uint32_t)bin; rfin = r - cum; found = true; }
        cum = nc;
    }
    ws[WS_PREF + col] = v;
    ws[WS_REM + col] = rfin;
}

// ---- 3) collect boundary-bucket candidates (sharded per-column atomics) ----
__global__ __launch_bounds__(256) void kcollect(const float* __restrict__ xf, const float* __restrict__ mask,
                                                uint32_t* __restrict__ ws) {
    __shared__ uint32_t lp[32];
    __shared__ float lmin;
    const int b = blockIdx.x >> 7;
    const int blk = blockIdx.x & 127;
    const int tid = threadIdx.x;
    if (tid < 32) lp[tid] = ws[WS_PREF + b * 32 + tid];
    if (tid == 0) lmin = __uint_as_float(ws[WS_MIN]);
    __syncthreads();
    const float4* x4 = (const float4*)xf + (size_t)b * 524288;
    const float mn = lmin;
    uint64_t* cand = (uint64_t*)(ws + WS_CAND);
#pragma unroll
    for (int c = 0; c < 2; ++c) {
        float4 v[8];
#pragma unroll
        for (int k = 0; k < 8; ++k) v[k] = x4[blk * 4096 + c * 2048 + k * 256 + tid];
#pragma unroll
        for (int k = 0; k < 8; ++k) {
            const int e = blk * 4096 + c * 2048 + k * 256 + tid;
            const int n = e >> 3;
            const int fb = (e & 7) * 4;
            float vv[4] = {v[k].x, v[k].y, v[k].z, v[k].w};
#pragma unroll
            for (int j = 0; j < 4; ++j) {
                uint32_t key = fkey(vv[j]);
                if ((key >> 23) == lp[fb + j]) {
                    float mk = mask[(size_t)b * NN + n];
                    float sv = ((vv[j] + mn) + EPSF) * mk;
                    uint32_t skey = fkey(sv);
                    uint32_t col = (uint32_t)(b * 32 + fb + j);
                    uint32_t shard = (tid >> 3) & 7;
                    uint32_t idx = atomicAdd(&ws[WS_EQC + col * 8 + shard], 1u);
                    if (idx < CAP_SHARD)
                        cand[(size_t)col * CAP_COL + shard * CAP_SHARD + idx] =
                            ((uint64_t)skey << 32) | (uint32_t)(~(uint32_t)n);
                }
            }
        }
    }
}

// ---- 4) per-column exact threshold: radix-select r-th largest u64 (skey,~n) ----
__global__ __launch_bounds__(256) void kthresh(uint32_t* __restrict__ ws) {
    __shared__ uint32_t h[256];
    __shared__ uint64_t buf[4096];
    __shared__ uint32_t sh_bin, sh_rr, sh_lcnt;
    const int col = blockIdx.x;
    const int tid = threadIdx.x;
    uint32_t cs[8];
    uint32_t total = 0;
#pragma unroll
    for (int s = 0; s < 8; ++s) {
        uint32_t c = ws[WS_EQC + col * 8 + s];
        cs[s] = c > CAP_SHARD ? (uint32_t)CAP_SHARD : c;
        total += cs[s];
    }
    uint32_t rr = ws[WS_REM + col];
    if (rr > total) rr = total;
    if (rr == 0) rr = 1;
    const uint64_t* cand = (const uint64_t*)(ws + WS_CAND) + (size_t)col * CAP_COL;
    uint64_t prefix = 0;
    bool lds = false;
    uint32_t lcnt = 0;
    for (int d = 0; d < 8; ++d) {
        h[tid] = 0;
        if (tid == 0) sh_lcnt = 0;
        __syncthreads();
        const int sh = 56 - 8 * d;
        if (!lds) {
            for (int s = 0; s < 8; ++s)
                for (uint32_t i = tid; i < cs[s]; i += 256) {
                    uint64_t v = cand[s * CAP_SHARD + i];
                    if (d == 0 || (v >> (sh + 8)) == prefix)
                        atomicAdd(&h[(uint32_t)(v >> sh) & 255u], 1u);
                }
        } else {
            for (uint32_t i = tid; i < lcnt; i += 256) {
                uint64_t v = buf[i];
                if ((v >> (sh + 8)) == prefix)
                    atomicAdd(&h[(uint32_t)(v >> sh) & 255u], 1u);
            }
        }
        __syncthreads();
        // suffix (descending) scan: h[b] = sum_{b' >= b} count[b']
        for (int off = 1; off < 256; off <<= 1) {
            uint32_t t = (tid + off < 256) ? h[tid + off] : 0;
            __syncthreads();
            h[tid] += t;
            __syncthreads();
        }
        uint32_t Sb = h[tid];
        uint32_t Sb1 = (tid < 255) ? h[tid + 1] : 0;
        if (Sb >= rr && Sb1 < rr) { sh_bin = (uint32_t)tid; sh_rr = rr - Sb1; }
        __syncthreads();
        prefix = (prefix << 8) | sh_bin;
        rr = sh_rr;
        __syncthreads();
        if (!lds && d == 1) {
            // compact: only candidates matching the 16-bit prefix survive (~40/col)
            for (int s = 0; s < 8; ++s)
                for (uint32_t i = tid; i < cs[s]; i += 256) {
                    uint64_t v = cand[s * CAP_SHARD + i];
                    if ((v >> 48) == prefix) {
                        uint32_t idx = atomicAdd(&sh_lcnt, 1u);
                        if (idx < 4096u) buf[idx] = v;
                    }
                }
            __syncthreads();
            if (sh_lcnt <= 4096u) { lds = true; lcnt = sh_lcnt; }
            __syncthreads();
        }
    }
    if (tid == 0) ((uint64_t*)(ws + WS_T))[col] = prefix;
}

// ---- 5) mark: exact selection per element; coalesced NT output writes ----
__global__ __launch_bounds__(256) void kmark(const float* __restrict__ xf, const float* __restrict__ mask,
                                             uint32_t* __restrict__ ws, float* __restrict__ upd,
                                             float* __restrict__ omask) {
    __shared__ uint32_t lp[32];
    __shared__ uint64_t lT[32];
    __shared__ float lmin;
    const int b = blockIdx.x >> 7;
    const int blk = blockIdx.x & 127;
    const int tid = threadIdx.x;
    if (tid < 32) {
        lp[tid] = ws[WS_PREF + b * 32 + tid];
        lT[tid] = ((const uint64_t*)(ws + WS_T))[b * 32 + tid];
    }
    if (tid == 0) lmin = __uint_as_float(ws[WS_MIN]);
    __syncthreads();
    const float4* x4 = (const float4*)xf + (size_t)b * 524288;
    f4v* o4 = (f4v*)omask + (size_t)b * 524288;
    const float mn = lmin;
    const int lane = tid & 63;
#pragma unroll
    for (int c = 0; c < 2; ++c) {
        float4 v[8];
#pragma unroll
        for (int k = 0; k < 8; ++k) v[k] = x4[blk * 4096 + c * 2048 + k * 256 + tid];
#pragma unroll
        for (int k = 0; k < 8; ++k) {
            const int e = blk * 4096 + c * 2048 + k * 256 + tid;
            const int n = e >> 3;
            const int fb = (e & 7) * 4;
            float vv[4] = {v[k].x, v[k].y, v[k].z, v[k].w};
            bool sel = false;
#pragma unroll
            for (int j = 0; j < 4; ++j) {
                uint32_t key = fkey(vv[j]);
                uint32_t k9 = key >> 23;
                uint32_t p = lp[fb + j];
                if (k9 > p) {
                    sel = true;
                } else if (k9 == p) {
                    float mk = mask[(size_t)b * NN + n];
                    float sv = ((vv[j] + mn) + EPSF) * mk;
                    uint64_t kk = ((uint64_t)fkey(sv) << 32) | (uint32_t)(~(uint32_t)n);
                    if (kk >= lT[fb + j]) sel = true;
                }
            }
            unsigned long long bal = __ballot(sel);
            uint32_t grp = (uint32_t)(bal >> (lane & 56)) & 0xFFu;
            float u1 = grp ? 1.0f : 0.0f;
            f4v o;
            o.x = vv[0] * u1; o.y = vv[1] * u1; o.z = vv[2] * u1; o.w = vv[3] * u1;
            __builtin_nontemporal_store(o, &o4[e]);
            if ((tid & 7) == 0) __builtin_nontemporal_store(u1, &upd[(size_t)b * NN + n]);
        }
    }
}

extern "C" void kernel_launch(void* const* d_in, const int* in_sizes, int n_in,
                              void* d_out, int out_size, void* d_ws, size_t ws_size,
                              hipStream_t stream) {
    const float* x = (const float*)d_in[0];
    const float* mask = (const float*)d_in[1];
    float* upd = (float*)d_out;                       // (B,N,1)
    float* omask = (float*)d_out + (size_t)BB * NN;   // (B,N,F)
    uint32_t* ws = (uint32_t*)d_ws;

    hipMemsetAsync((char*)d_ws + (size_t)WS_MIN * 4, 0xFF, 4, stream);
    hipMemsetAsync((char*)d_ws + (size_t)WS_EQC * 4, 0, (size_t)(4096 + NBIN * 512) * 4, stream);

    khist<<<BB * 32, 512, 0, stream>>>(x, ws);
    kresolve<<<1, 512, 0, stream>>>(ws);
    kcollect<<<BB * 128, 256, 0, stream>>>(x, mask, ws);
    kthresh<<<512, 256, 0, stream>>>(ws);
    kmark<<<BB * 128, 256, 0, stream>>>(x, mask, ws, upd, omask);
}

// Round 6
// 340.153 us; speedup vs baseline: 1.5644x; 1.5644x over previous
//
#include <hip/hip_runtime.h>
#include <stdint.h>

#define BB   16
#define NN   65536
#define FF   32
#define KSEL 16384
#define EPSF 1e-10f
#define NBIN 512                 // 9-bit first radix: sign + 8 exp bits
#define SEGH 32                  // khist segments per batch
#define CAP_COL 11264            // candidates per column (λ≈9825, +16σ)
#define CAP_LDS 128              // LDS staged candidates per feature per block

typedef float f4v __attribute__((ext_vector_type(4)));

// ---- workspace layout (uint32 element offsets), ~47 MB ----
#define WS_MIN   0                          // 1 (memset 0xFF)
#define WS_PREF  8                          // [512]
#define WS_REM   520                        // [512]
#define WS_T     1032                       // u64[512] (byte 4128, 8-aligned)
#define WS_EQC   2056                       // [512] candidate counters (memset 0)
#define WS_HIST  2568                       // [512][512] reduced hist
#define WS_CAND  264712                     // u64[512][CAP_COL]  (byte 1058848)
#define WS_PART  WS_CAND                    // [SEGH][512][512] partials ALIAS cand (consumed first)

__device__ __forceinline__ uint32_t fkey(float s) {
    uint32_t u = __float_as_uint(s);
    return (u & 0x80000000u) ? ~u : (u | 0x80000000u);
}

// ---- 1) fused min(|x|) + 9-bit hist; LDS hist -> plain partial writes ----
__global__ __launch_bounds__(512) void khist(const float* __restrict__ xf, uint32_t* __restrict__ ws) {
    __shared__ uint32_t lh[NBIN * 33];
    __shared__ uint32_t rmin[512];
    const int b = blockIdx.x >> 5;
    const int s = blockIdx.x & 31;
    const int tid = threadIdx.x;
    for (int i = tid; i < NBIN * 33; i += 512) lh[i] = 0;
    __syncthreads();
    const float4* x4 = (const float4*)xf + (size_t)b * (NN * FF / 4) + (size_t)s * 16384;
    uint32_t mreg = 0xFFFFFFFFu;
#pragma unroll
    for (int c = 0; c < 4; ++c) {
        float4 v[8];
#pragma unroll
        for (int k = 0; k < 8; ++k) v[k] = x4[c * 4096 + k * 512 + tid];
#pragma unroll
        for (int k = 0; k < 8; ++k) {
            const int e = c * 4096 + k * 512 + tid;
            const int fb = (e & 7) * 4;
            float vv[4] = {v[k].x, v[k].y, v[k].z, v[k].w};
#pragma unroll
            for (int j = 0; j < 4; ++j) {
                uint32_t u = __float_as_uint(vv[j]);
                uint32_t a = u & 0x7FFFFFFFu;
                mreg = a < mreg ? a : mreg;
                uint32_t key = (u & 0x80000000u) ? ~u : (u | 0x80000000u);
                atomicAdd(&lh[(key >> 23) * 33 + fb + j], 1u);
            }
        }
    }
    rmin[tid] = mreg;
    __syncthreads();
    for (int off = 256; off > 0; off >>= 1) {
        if (tid < off) { uint32_t o = rmin[tid + off]; if (o < rmin[tid]) rmin[tid] = o; }
        __syncthreads();
    }
    if (tid == 0) atomicMin(&ws[WS_MIN], rmin[0]);
    uint32_t* part = ws + WS_PART;
    for (int k = tid; k < NBIN * 32; k += 512) {
        const int bin = k >> 5, f = k & 31;
        part[((size_t)(s * NBIN + bin)) * 512 + b * 32 + f] = lh[bin * 33 + f];
    }
}

// ---- 2) reduce partials over segments ----
__global__ __launch_bounds__(512) void kreduce(uint32_t* __restrict__ ws) {
    const int bin = blockIdx.x;
    const int col = threadIdx.x;
    const uint32_t* part = ws + WS_PART;
    uint32_t sum = 0;
#pragma unroll 8
    for (int s = 0; s < SEGH; ++s) sum += part[((size_t)(s * NBIN + bin)) * 512 + col];
    ws[WS_HIST + bin * 512 + col] = sum;
}

// ---- 3) per-column: bucket containing rank-K + remaining rank ----
__global__ __launch_bounds__(512) void kresolve(uint32_t* __restrict__ ws) {
    const int col = threadIdx.x;
    const uint32_t* hist = ws + WS_HIST;
    uint32_t r = KSEL, cum = 0, v = 0, rfin = 1;
    bool found = false;
    for (int bin = NBIN - 1; bin >= 0; --bin) {
        uint32_t h = hist[bin * 512 + col];
        uint32_t nc = cum + h;
        if (!found && nc >= r) { v = (uint32_t)bin; rfin = r - cum; found = true; }
        cum = nc;
    }
    ws[WS_PREF + col] = v;
    ws[WS_REM + col] = rfin;
}

// ---- 4) collect boundary candidates: LDS staging + coalesced flush ----
__global__ __launch_bounds__(256) void kcollect(const float* __restrict__ xf, const float* __restrict__ mask,
                                                uint32_t* __restrict__ ws) {
    __shared__ uint64_t lbuf[32][CAP_LDS];
    __shared__ uint32_t lcnt[32], lbase[32], lp[32];
    __shared__ float lmin;
    const int b = blockIdx.x >> 7;
    const int blk = blockIdx.x & 127;
    const int tid = threadIdx.x;
    if (tid < 32) { lp[tid] = ws[WS_PREF + b * 32 + tid]; lcnt[tid] = 0; }
    if (tid == 0) lmin = __uint_as_float(ws[WS_MIN]);
    __syncthreads();
    const float4* x4 = (const float4*)xf + (size_t)b * 524288;
    const float mn = lmin;
    uint64_t* gcand = (uint64_t*)(ws + WS_CAND);
#pragma unroll
    for (int c = 0; c < 2; ++c) {
        float4 v[8];
#pragma unroll
        for (int k = 0; k < 8; ++k) v[k] = x4[blk * 4096 + c * 2048 + k * 256 + tid];
#pragma unroll
        for (int k = 0; k < 8; ++k) {
            const int e = blk * 4096 + c * 2048 + k * 256 + tid;
            const int n = e >> 3;
            const int fb = (e & 7) * 4;
            float vv[4] = {v[k].x, v[k].y, v[k].z, v[k].w};
#pragma unroll
            for (int j = 0; j < 4; ++j) {
                uint32_t key = fkey(vv[j]);
                const int f = fb + j;
                if ((key >> 23) == lp[f]) {
                    float mk = mask[(size_t)b * NN + n];
                    float sv = ((vv[j] + mn) + EPSF) * mk;
                    uint64_t v64 = ((uint64_t)fkey(sv) << 32) | (uint32_t)(~(uint32_t)n);
                    uint32_t idx = atomicAdd(&lcnt[f], 1u);
                    if (idx < CAP_LDS) {
                        lbuf[f][idx] = v64;
                    } else {           // rare spill: reserve directly (disjoint from flush ranges)
                        uint32_t col = (uint32_t)(b * 32 + f);
                        uint32_t pos = atomicAdd(&ws[WS_EQC + col], 1u);
                        if (pos < CAP_COL) gcand[(size_t)col * CAP_COL + pos] = v64;
                    }
                }
            }
        }
    }
    __syncthreads();
    if (tid < 32) {
        uint32_t c = lcnt[tid];
        if (c > CAP_LDS) c = CAP_LDS;
        lcnt[tid] = c;
        lbase[tid] = atomicAdd(&ws[WS_EQC + b * 32 + tid], c);
    }
    __syncthreads();
    for (int f = 0; f < 32; ++f) {
        const uint32_t c = lcnt[f], base = lbase[f];
        const size_t cb = (size_t)(b * 32 + f) * CAP_COL;
        for (uint32_t i = tid; i < c; i += 256) {
            uint32_t pos = base + i;
            if (pos < CAP_COL) gcand[cb + pos] = lbuf[f][i];
        }
    }
}

// ---- 5) per-column exact threshold: radix-select r-th largest u64 ----
__global__ __launch_bounds__(256) void kthresh(uint32_t* __restrict__ ws) {
    __shared__ uint32_t h[256];
    __shared__ uint64_t buf[4096];
    __shared__ uint32_t sh_bin, sh_rr, sh_lcnt;
    const int col = blockIdx.x;
    const int tid = threadIdx.x;
    uint32_t cnt = ws[WS_EQC + col];
    if (cnt > CAP_COL) cnt = CAP_COL;
    uint32_t rr = ws[WS_REM + col];
    if (rr > cnt) rr = cnt;
    if (rr == 0) rr = 1;
    const uint64_t* cand = (const uint64_t*)(ws + WS_CAND) + (size_t)col * CAP_COL;
    uint64_t prefix = 0;
    bool lds = false;
    uint32_t lcnt = 0;
    for (int d = 0; d < 8; ++d) {
        h[tid] = 0;
        if (tid == 0) sh_lcnt = 0;
        __syncthreads();
        const int sh = 56 - 8 * d;
        if (!lds) {
            for (uint32_t i = tid; i < cnt; i += 256) {
                uint64_t v = cand[i];
                if (d == 0 || (v >> (sh + 8)) == prefix)
                    atomicAdd(&h[(uint32_t)(v >> sh) & 255u], 1u);
            }
        } else {
            for (uint32_t i = tid; i < lcnt; i += 256) {
                uint64_t v = buf[i];
                if ((v >> (sh + 8)) == prefix)
                    atomicAdd(&h[(uint32_t)(v >> sh) & 255u], 1u);
            }
        }
        __syncthreads();
        for (int off = 1; off < 256; off <<= 1) {   // suffix scan
            uint32_t t = (tid + off < 256) ? h[tid + off] : 0;
            __syncthreads();
            h[tid] += t;
            __syncthreads();
        }
        uint32_t Sb = h[tid];
        uint32_t Sb1 = (tid < 255) ? h[tid + 1] : 0;
        if (Sb >= rr && Sb1 < rr) { sh_bin = (uint32_t)tid; sh_rr = rr - Sb1; }
        __syncthreads();
        prefix = (prefix << 8) | sh_bin;
        rr = sh_rr;
        __syncthreads();
        if (!lds && d == 1) {
            for (uint32_t i = tid; i < cnt; i += 256) {
                uint64_t v = cand[i];
                if ((v >> 48) == prefix) {
                    uint32_t idx = atomicAdd(&sh_lcnt, 1u);
                    if (idx < 4096u) buf[idx] = v;
                }
            }
            __syncthreads();
            if (sh_lcnt <= 4096u) { lds = true; lcnt = sh_lcnt; }
            __syncthreads();
        }
    }
    if (tid == 0) ((uint64_t*)(ws + WS_T))[col] = prefix;
}

// ---- 6) mark: exact selection per element; coalesced NT output writes ----
__global__ __launch_bounds__(256) void kmark(const float* __restrict__ xf, const float* __restrict__ mask,
                                             uint32_t* __restrict__ ws, float* __restrict__ upd,
                                             float* __restrict__ omask) {
    __shared__ uint32_t lp[32];
    __shared__ uint64_t lT[32];
    __shared__ float lmin;
    const int b = blockIdx.x >> 7;
    const int blk = blockIdx.x & 127;
    const int tid = threadIdx.x;
    if (tid < 32) {
        lp[tid] = ws[WS_PREF + b * 32 + tid];
        lT[tid] = ((const uint64_t*)(ws + WS_T))[b * 32 + tid];
    }
    if (tid == 0) lmin = __uint_as_float(ws[WS_MIN]);
    __syncthreads();
    const float4* x4 = (const float4*)xf + (size_t)b * 524288;
    f4v* o4 = (f4v*)omask + (size_t)b * 524288;
    const float mn = lmin;
    const int lane = tid & 63;
#pragma unroll
    for (int c = 0; c < 2; ++c) {
        float4 v[8];
#pragma unroll
        for (int k = 0; k < 8; ++k) v[k] = x4[blk * 4096 + c * 2048 + k * 256 + tid];
#pragma unroll
        for (int k = 0; k < 8; ++k) {
            const int e = blk * 4096 + c * 2048 + k * 256 + tid;
            const int n = e >> 3;
            const int fb = (e & 7) * 4;
            float vv[4] = {v[k].x, v[k].y, v[k].z, v[k].w};
            bool sel = false;
#pragma unroll
            for (int j = 0; j < 4; ++j) {
                uint32_t key = fkey(vv[j]);
                uint32_t k9 = key >> 23;
                uint32_t p = lp[fb + j];
                if (k9 > p) {
                    sel = true;
                } else if (k9 == p) {
                    float mk = mask[(size_t)b * NN + n];
                    float sv = ((vv[j] + mn) + EPSF) * mk;
                    uint64_t kk = ((uint64_t)fkey(sv) << 32) | (uint32_t)(~(uint32_t)n);
                    if (kk >= lT[fb + j]) sel = true;
                }
            }
            unsigned long long bal = __ballot(sel);
            uint32_t grp = (uint32_t)(bal >> (lane & 56)) & 0xFFu;
            float u1 = grp ? 1.0f : 0.0f;
            f4v o;
            o.x = vv[0] * u1; o.y = vv[1] * u1; o.z = vv[2] * u1; o.w = vv[3] * u1;
            __builtin_nontemporal_store(o, &o4[e]);
            if ((tid & 7) == 0) __builtin_nontemporal_store(u1, &upd[(size_t)b * NN + n]);
        }
    }
}

extern "C" void kernel_launch(void* const* d_in, const int* in_sizes, int n_in,
                              void* d_out, int out_size, void* d_ws, size_t ws_size,
                              hipStream_t stream) {
    const float* x = (const float*)d_in[0];
    const float* mask = (const float*)d_in[1];
    float* upd = (float*)d_out;                       // (B,N,1)
    float* omask = (float*)d_out + (size_t)BB * NN;   // (B,N,F)
    uint32_t* ws = (uint32_t*)d_ws;

    hipMemsetAsync((char*)d_ws + (size_t)WS_MIN * 4, 0xFF, 4, stream);
    hipMemsetAsync((char*)d_ws + (size_t)WS_EQC * 4, 0, 512 * 4, stream);

    khist<<<BB * SEGH, 512, 0, stream>>>(x, ws);
    kreduce<<<NBIN, 512, 0, stream>>>(ws);
    kresolve<<<1, 512, 0, stream>>>(ws);
    kcollect<<<BB * 128, 256, 0, stream>>>(x, mask, ws);
    kthresh<<<512, 256, 0, stream>>>(ws);
    kmark<<<BB * 128, 256, 0, stream>>>(x, mask, ws, upd, omask);
}

// Round 7
// 209.854 us; speedup vs baseline: 2.5358x; 1.6209x over previous
//
#include <hip/hip_runtime.h>
#include <stdint.h>

#define BB   16
#define NN   65536
#define FF   32
#define KSEL 16384
#define EPSF 1e-10f
#define NBIN 512                 // 9-bit first radix: sign + 8 exp bits
#define SEGH 32                  // khist segments per batch
#define CAP_COL 11264            // candidates per column (λ≈9825, +16σ)
#define CAP_LDS 128              // LDS staged candidates per feature per block

typedef float f4v __attribute__((ext_vector_type(4)));

// ---- workspace layout (uint32 element offsets), ~47 MB ----
#define WS_MIN   0                          // 1 (memset 0xFF)
#define WS_PREF  8                          // [512]
#define WS_REM   520                        // [512]
#define WS_T     1032                       // u64[512] (byte 4128, 8-aligned)
#define WS_EQC   2056                       // [512] candidate counters (memset 0)
#define WS_HIST  2568                       // [512][512] reduced hist
#define WS_CAND  264712                     // u64[512][CAP_COL]  (byte 1058848)
#define WS_PART  WS_CAND                    // [SEGH][512][512] partials ALIAS cand (consumed first)

__device__ __forceinline__ uint32_t fkey(float s) {
    uint32_t u = __float_as_uint(s);
    return (u & 0x80000000u) ? ~u : (u | 0x80000000u);
}

// ---- 1) fused min(|x|) + 9-bit hist; LDS hist -> plain partial writes ----
__global__ __launch_bounds__(512) void khist(const float* __restrict__ xf, uint32_t* __restrict__ ws) {
    __shared__ uint32_t lh[NBIN * 33];
    __shared__ uint32_t rmin[512];
    const int b = blockIdx.x >> 5;
    const int s = blockIdx.x & 31;
    const int tid = threadIdx.x;
    for (int i = tid; i < NBIN * 33; i += 512) lh[i] = 0;
    __syncthreads();
    const float4* x4 = (const float4*)xf + (size_t)b * (NN * FF / 4) + (size_t)s * 16384;
    uint32_t mreg = 0xFFFFFFFFu;
#pragma unroll
    for (int c = 0; c < 4; ++c) {
        float4 v[8];
#pragma unroll
        for (int k = 0; k < 8; ++k) v[k] = x4[c * 4096 + k * 512 + tid];
#pragma unroll
        for (int k = 0; k < 8; ++k) {
            const int e = c * 4096 + k * 512 + tid;
            const int fb = (e & 7) * 4;
            float vv[4] = {v[k].x, v[k].y, v[k].z, v[k].w};
#pragma unroll
            for (int j = 0; j < 4; ++j) {
                uint32_t u = __float_as_uint(vv[j]);
                uint32_t a = u & 0x7FFFFFFFu;
                mreg = a < mreg ? a : mreg;
                uint32_t key = (u & 0x80000000u) ? ~u : (u | 0x80000000u);
                atomicAdd(&lh[(key >> 23) * 33 + fb + j], 1u);
            }
        }
    }
    rmin[tid] = mreg;
    __syncthreads();
    for (int off = 256; off > 0; off >>= 1) {
        if (tid < off) { uint32_t o = rmin[tid + off]; if (o < rmin[tid]) rmin[tid] = o; }
        __syncthreads();
    }
    if (tid == 0) atomicMin(&ws[WS_MIN], rmin[0]);
    uint32_t* part = ws + WS_PART;
    for (int k = tid; k < NBIN * 32; k += 512) {
        const int bin = k >> 5, f = k & 31;
        part[((size_t)(s * NBIN + bin)) * 512 + b * 32 + f] = lh[bin * 33 + f];
    }
}

// ---- 2) reduce partials over segments ----
__global__ __launch_bounds__(512) void kreduce(uint32_t* __restrict__ ws) {
    const int bin = blockIdx.x;
    const int col = threadIdx.x;
    const uint32_t* part = ws + WS_PART;
    uint32_t sum = 0;
#pragma unroll 8
    for (int s = 0; s < SEGH; ++s) sum += part[((size_t)(s * NBIN + bin)) * 512 + col];
    ws[WS_HIST + bin * 512 + col] = sum;
}

// ---- 3) per-column (one block/col): suffix-scan bins in LDS, find rank-K bucket ----
__global__ __launch_bounds__(512) void kresolve(uint32_t* __restrict__ ws) {
    __shared__ uint32_t h[512];
    const int col = blockIdx.x;
    const int bin = threadIdx.x;
    h[bin] = ws[WS_HIST + bin * 512 + col];
    __syncthreads();
    for (int off = 1; off < 512; off <<= 1) {        // S[b] = sum_{b'>=b} h[b']
        uint32_t t = (bin + off < 512) ? h[bin + off] : 0;
        __syncthreads();
        h[bin] += t;
        __syncthreads();
    }
    uint32_t Sb = h[bin];
    uint32_t Sb1 = (bin < 511) ? h[bin + 1] : 0;
    if (Sb >= (uint32_t)KSEL && Sb1 < (uint32_t)KSEL) {
        ws[WS_PREF + col] = (uint32_t)bin;
        ws[WS_REM + col] = (uint32_t)KSEL - Sb1;
    }
}

// ---- 4) collect boundary candidates: LDS staging + coalesced flush ----
__global__ __launch_bounds__(256) void kcollect(const float* __restrict__ xf, const float* __restrict__ mask,
                                                uint32_t* __restrict__ ws) {
    __shared__ uint64_t lbuf[32][CAP_LDS];
    __shared__ uint32_t lcnt[32], lbase[32], lp[32];
    __shared__ float lmin;
    const int b = blockIdx.x >> 7;
    const int blk = blockIdx.x & 127;
    const int tid = threadIdx.x;
    if (tid < 32) { lp[tid] = ws[WS_PREF + b * 32 + tid]; lcnt[tid] = 0; }
    if (tid == 0) lmin = __uint_as_float(ws[WS_MIN]);
    __syncthreads();
    const float4* x4 = (const float4*)xf + (size_t)b * 524288;
    const float mn = lmin;
    uint64_t* gcand = (uint64_t*)(ws + WS_CAND);
#pragma unroll
    for (int c = 0; c < 2; ++c) {
        float4 v[8];
#pragma unroll
        for (int k = 0; k < 8; ++k) v[k] = x4[blk * 4096 + c * 2048 + k * 256 + tid];
#pragma unroll
        for (int k = 0; k < 8; ++k) {
            const int e = blk * 4096 + c * 2048 + k * 256 + tid;
            const int n = e >> 3;
            const int fb = (e & 7) * 4;
            float vv[4] = {v[k].x, v[k].y, v[k].z, v[k].w};
#pragma unroll
            for (int j = 0; j < 4; ++j) {
                uint32_t key = fkey(vv[j]);
                const int f = fb + j;
                if ((key >> 23) == lp[f]) {
                    float mk = mask[(size_t)b * NN + n];
                    float sv = ((vv[j] + mn) + EPSF) * mk;
                    uint64_t v64 = ((uint64_t)fkey(sv) << 32) | (uint32_t)(~(uint32_t)n);
                    uint32_t idx = atomicAdd(&lcnt[f], 1u);
                    if (idx < CAP_LDS) {
                        lbuf[f][idx] = v64;
                    } else {           // rare spill: reserve directly (disjoint from flush ranges)
                        uint32_t col = (uint32_t)(b * 32 + f);
                        uint32_t pos = atomicAdd(&ws[WS_EQC + col], 1u);
                        if (pos < CAP_COL) gcand[(size_t)col * CAP_COL + pos] = v64;
                    }
                }
            }
        }
    }
    __syncthreads();
    if (tid < 32) {
        uint32_t c = lcnt[tid];
        if (c > CAP_LDS) c = CAP_LDS;
        lcnt[tid] = c;
        lbase[tid] = atomicAdd(&ws[WS_EQC + b * 32 + tid], c);
    }
    __syncthreads();
    for (int f = 0; f < 32; ++f) {
        const uint32_t c = lcnt[f], base = lbase[f];
        const size_t cb = (size_t)(b * 32 + f) * CAP_COL;
        for (uint32_t i = tid; i < c; i += 256) {
            uint32_t pos = base + i;
            if (pos < CAP_COL) gcand[cb + pos] = lbuf[f][i];
        }
    }
}

// ---- 5) per-column exact threshold: radix-select r-th largest u64 ----
__global__ __launch_bounds__(256) void kthresh(uint32_t* __restrict__ ws) {
    __shared__ uint32_t h[256];
    __shared__ uint64_t buf[4096];
    __shared__ uint32_t sh_bin, sh_rr, sh_lcnt;
    const int col = blockIdx.x;
    const int tid = threadIdx.x;
    uint32_t cnt = ws[WS_EQC + col];
    if (cnt > CAP_COL) cnt = CAP_COL;
    uint32_t rr = ws[WS_REM + col];
    if (rr > cnt) rr = cnt;
    if (rr == 0) rr = 1;
    const uint64_t* cand = (const uint64_t*)(ws + WS_CAND) + (size_t)col * CAP_COL;
    uint64_t prefix = 0;
    bool lds = false;
    uint32_t lcnt = 0;
    for (int d = 0; d < 8; ++d) {
        h[tid] = 0;
        if (tid == 0) sh_lcnt = 0;
        __syncthreads();
        const int sh = 56 - 8 * d;
        if (!lds) {
            for (uint32_t i = tid; i < cnt; i += 256) {
                uint64_t v = cand[i];
                if (d == 0 || (v >> (sh + 8)) == prefix)
                    atomicAdd(&h[(uint32_t)(v >> sh) & 255u], 1u);
            }
        } else {
            for (uint32_t i = tid; i < lcnt; i += 256) {
                uint64_t v = buf[i];
                if ((v >> (sh + 8)) == prefix)
                    atomicAdd(&h[(uint32_t)(v >> sh) & 255u], 1u);
            }
        }
        __syncthreads();
        for (int off = 1; off < 256; off <<= 1) {   // suffix scan
            uint32_t t = (tid + off < 256) ? h[tid + off] : 0;
            __syncthreads();
            h[tid] += t;
            __syncthreads();
        }
        uint32_t Sb = h[tid];
        uint32_t Sb1 = (tid < 255) ? h[tid + 1] : 0;
        if (Sb >= rr && Sb1 < rr) { sh_bin = (uint32_t)tid; sh_rr = rr - Sb1; }
        __syncthreads();
        prefix = (prefix << 8) | sh_bin;
        rr = sh_rr;
        __syncthreads();
        if (!lds && d == 1) {
            for (uint32_t i = tid; i < cnt; i += 256) {
                uint64_t v = cand[i];
                if ((v >> 48) == prefix) {
                    uint32_t idx = atomicAdd(&sh_lcnt, 1u);
                    if (idx < 4096u) buf[idx] = v;
                }
            }
            __syncthreads();
            if (sh_lcnt <= 4096u) { lds = true; lcnt = sh_lcnt; }
            __syncthreads();
        }
    }
    if (tid == 0) ((uint64_t*)(ws + WS_T))[col] = prefix;
}

// ---- 6) mark: exact selection per element; coalesced NT output writes ----
__global__ __launch_bounds__(256) void kmark(const float* __restrict__ xf, const float* __restrict__ mask,
                                             uint32_t* __restrict__ ws, float* __restrict__ upd,
                                             float* __restrict__ omask) {
    __shared__ uint32_t lp[32];
    __shared__ uint64_t lT[32];
    __shared__ float lmin;
    const int b = blockIdx.x >> 7;
    const int blk = blockIdx.x & 127;
    const int tid = threadIdx.x;
    if (tid < 32) {
        lp[tid] = ws[WS_PREF + b * 32 + tid];
        lT[tid] = ((const uint64_t*)(ws + WS_T))[b * 32 + tid];
    }
    if (tid == 0) lmin = __uint_as_float(ws[WS_MIN]);
    __syncthreads();
    const float4* x4 = (const float4*)xf + (size_t)b * 524288;
    f4v* o4 = (f4v*)omask + (size_t)b * 524288;
    const float mn = lmin;
    const int lane = tid & 63;
#pragma unroll
    for (int c = 0; c < 2; ++c) {
        float4 v[8];
#pragma unroll
        for (int k = 0; k < 8; ++k) v[k] = x4[blk * 4096 + c * 2048 + k * 256 + tid];
#pragma unroll
        for (int k = 0; k < 8; ++k) {
            const int e = blk * 4096 + c * 2048 + k * 256 + tid;
            const int n = e >> 3;
            const int fb = (e & 7) * 4;
            float vv[4] = {v[k].x, v[k].y, v[k].z, v[k].w};
            bool sel = false;
#pragma unroll
            for (int j = 0; j < 4; ++j) {
                uint32_t key = fkey(vv[j]);
                uint32_t k9 = key >> 23;
                uint32_t p = lp[fb + j];
                if (k9 > p) {
                    sel = true;
                } else if (k9 == p) {
                    float mk = mask[(size_t)b * NN + n];
                    float sv = ((vv[j] + mn) + EPSF) * mk;
                    uint64_t kk = ((uint64_t)fkey(sv) << 32) | (uint32_t)(~(uint32_t)n);
                    if (kk >= lT[fb + j]) sel = true;
                }
            }
            unsigned long long bal = __ballot(sel);
            uint32_t grp = (uint32_t)(bal >> (lane & 56)) & 0xFFu;
            float u1 = grp ? 1.0f : 0.0f;
            f4v o;
            o.x = vv[0] * u1; o.y = vv[1] * u1; o.z = vv[2] * u1; o.w = vv[3] * u1;
            __builtin_nontemporal_store(o, &o4[e]);
            if ((tid & 7) == 0) __builtin_nontemporal_store(u1, &upd[(size_t)b * NN + n]);
        }
    }
}

extern "C" void kernel_launch(void* const* d_in, const int* in_sizes, int n_in,
                              void* d_out, int out_size, void* d_ws, size_t ws_size,
                              hipStream_t stream) {
    const float* x = (const float*)d_in[0];
    const float* mask = (const float*)d_in[1];
    float* upd = (float*)d_out;                       // (B,N,1)
    float* omask = (float*)d_out + (size_t)BB * NN;   // (B,N,F)
    uint32_t* ws = (uint32_t*)d_ws;

    hipMemsetAsync((char*)d_ws + (size_t)WS_MIN * 4, 0xFF, 4, stream);
    hipMemsetAsync((char*)d_ws + (size_t)WS_EQC * 4, 0, 512 * 4, stream);

    khist<<<BB * SEGH, 512, 0, stream>>>(x, ws);
    kreduce<<<NBIN, 512, 0, stream>>>(ws);
    kresolve<<<512, 512, 0, stream>>>(ws);
    kcollect<<<BB * 128, 256, 0, stream>>>(x, mask, ws);
    kthresh<<<512, 256, 0, stream>>>(ws);
    kmark<<<BB * 128, 256, 0, stream>>>(x, mask, ws, upd, omask);
}

// Round 8
// 199.154 us; speedup vs baseline: 2.6720x; 1.0537x over previous
//
#include <hip/hip_runtime.h>
#include <stdint.h>

#define BB   16
#define NN   65536
#define FF   32
#define KSEL 16384
#define EPSF 1e-10f
#define NBIN 512                 // 9-bit first radix: sign + 8 exp bits
#define SEGH 32                  // khist segments per batch
#define CAP_COL 11264            // candidates per column (λ≈9825, +16σ)
#define CAP_LDS 128              // LDS staged candidates per feature per block

typedef float f4v __attribute__((ext_vector_type(4)));

// ---- workspace layout (uint32 element offsets), ~46 MB ----
#define WS_MIN   0                          // 1 (memset 0xFF)
#define WS_PREF  8                          // [512]
#define WS_REM   520                        // [512]
#define WS_T     1032                       // u64[512] (byte 4128, 8-aligned)
#define WS_EQC   2056                       // [512] candidate counters (zeroed in kresolve)
#define WS_CAND  2568                       // u64[512][CAP_COL]  (byte 10272, 8-aligned)
#define WS_PART  WS_CAND                    // [512 col][SEGH][NBIN] u32 partials ALIAS cand
                                            // (written by khist, consumed by kresolve BEFORE kcollect writes cand)

__device__ __forceinline__ uint32_t fkey(float s) {
    uint32_t u = __float_as_uint(s);
    return (u & 0x80000000u) ? ~u : (u | 0x80000000u);
}

// ---- 1) fused min(|x|) + 9-bit hist; LDS hist -> NT partial writes [col][s][bin] ----
__global__ __launch_bounds__(512) void khist(const float* __restrict__ xf, uint32_t* __restrict__ ws) {
    __shared__ uint32_t lh[NBIN * 33];
    __shared__ uint32_t rmin[512];
    const int b = blockIdx.x >> 5;
    const int s = blockIdx.x & 31;
    const int tid = threadIdx.x;
    for (int i = tid; i < NBIN * 33; i += 512) lh[i] = 0;
    __syncthreads();
    const float4* x4 = (const float4*)xf + (size_t)b * (NN * FF / 4) + (size_t)s * 16384;
    uint32_t mreg = 0xFFFFFFFFu;
#pragma unroll
    for (int c = 0; c < 4; ++c) {
        float4 v[8];
#pragma unroll
        for (int k = 0; k < 8; ++k) v[k] = x4[c * 4096 + k * 512 + tid];
#pragma unroll
        for (int k = 0; k < 8; ++k) {
            const int e = c * 4096 + k * 512 + tid;
            const int fb = (e & 7) * 4;
            float vv[4] = {v[k].x, v[k].y, v[k].z, v[k].w};
#pragma unroll
            for (int j = 0; j < 4; ++j) {
                uint32_t u = __float_as_uint(vv[j]);
                uint32_t a = u & 0x7FFFFFFFu;
                mreg = a < mreg ? a : mreg;
                uint32_t key = (u & 0x80000000u) ? ~u : (u | 0x80000000u);
                atomicAdd(&lh[(key >> 23) * 33 + fb + j], 1u);
            }
        }
    }
    rmin[tid] = mreg;
    __syncthreads();
    for (int off = 256; off > 0; off >>= 1) {
        if (tid < off) { uint32_t o = rmin[tid + off]; if (o < rmin[tid]) rmin[tid] = o; }
        __syncthreads();
    }
    if (tid == 0) atomicMin(&ws[WS_MIN], rmin[0]);
    uint32_t* part = ws + WS_PART;
    // k = f*512 + bin; consecutive tid -> consecutive bin (coalesced 2KB runs)
    for (int k = tid; k < NBIN * 32; k += 512) {
        const int f = k >> 9, bin = k & 511;
        __builtin_nontemporal_store(lh[bin * 33 + f],
            &part[((size_t)(b * 32 + f) * SEGH + s) * NBIN + bin]);
    }
}

// ---- 2) fused reduce+resolve: one block per column; sum partials, suffix-scan, find bucket ----
__global__ __launch_bounds__(512) void kresolve(uint32_t* __restrict__ ws) {
    __shared__ uint32_t h[512];
    const int col = blockIdx.x;
    const int bin = threadIdx.x;
    const uint32_t* part = ws + WS_PART;
    uint32_t sum = 0;
#pragma unroll 8
    for (int s = 0; s < SEGH; ++s)
        sum += part[((size_t)col * SEGH + s) * NBIN + bin];
    h[bin] = sum;
    __syncthreads();
    for (int off = 1; off < 512; off <<= 1) {        // S[b] = sum_{b'>=b} h[b']
        uint32_t t = (bin + off < 512) ? h[bin + off] : 0;
        __syncthreads();
        h[bin] += t;
        __syncthreads();
    }
    uint32_t Sb = h[bin];
    uint32_t Sb1 = (bin < 511) ? h[bin + 1] : 0;
    if (Sb >= (uint32_t)KSEL && Sb1 < (uint32_t)KSEL) {
        ws[WS_PREF + col] = (uint32_t)bin;
        ws[WS_REM + col] = (uint32_t)KSEL - Sb1;
    }
    if (bin == 0) ws[WS_EQC + col] = 0;
}

// ---- 3) collect boundary candidates: LDS staging + coalesced NT flush ----
__global__ __launch_bounds__(256) void kcollect(const float* __restrict__ xf, const float* __restrict__ mask,
                                                uint32_t* __restrict__ ws) {
    __shared__ uint64_t lbuf[32][CAP_LDS];
    __shared__ uint32_t lcnt[32], lbase[32], lp[32];
    __shared__ float lmin;
    const int b = blockIdx.x >> 7;
    const int blk = blockIdx.x & 127;
    const int tid = threadIdx.x;
    if (tid < 32) { lp[tid] = ws[WS_PREF + b * 32 + tid]; lcnt[tid] = 0; }
    if (tid == 0) lmin = __uint_as_float(ws[WS_MIN]);
    __syncthreads();
    const float4* x4 = (const float4*)xf + (size_t)b * 524288;
    const float mn = lmin;
    uint64_t* gcand = (uint64_t*)(ws + WS_CAND);
#pragma unroll
    for (int c = 0; c < 2; ++c) {
        float4 v[8];
#pragma unroll
        for (int k = 0; k < 8; ++k) v[k] = x4[blk * 4096 + c * 2048 + k * 256 + tid];
#pragma unroll
        for (int k = 0; k < 8; ++k) {
            const int e = blk * 4096 + c * 2048 + k * 256 + tid;
            const int n = e >> 3;
            const int fb = (e & 7) * 4;
            float vv[4] = {v[k].x, v[k].y, v[k].z, v[k].w};
#pragma unroll
            for (int j = 0; j < 4; ++j) {
                uint32_t key = fkey(vv[j]);
                const int f = fb + j;
                if ((key >> 23) == lp[f]) {
                    float mk = mask[(size_t)b * NN + n];
                    float sv = ((vv[j] + mn) + EPSF) * mk;
                    uint64_t v64 = ((uint64_t)fkey(sv) << 32) | (uint32_t)(~(uint32_t)n);
                    uint32_t idx = atomicAdd(&lcnt[f], 1u);
                    if (idx < CAP_LDS) {
                        lbuf[f][idx] = v64;
                    } else {           // rare spill: reserve directly (disjoint from flush ranges)
                        uint32_t col = (uint32_t)(b * 32 + f);
                        uint32_t pos = atomicAdd(&ws[WS_EQC + col], 1u);
                        if (pos < CAP_COL)
                            __builtin_nontemporal_store(v64, &gcand[(size_t)col * CAP_COL + pos]);
                    }
                }
            }
        }
    }
    __syncthreads();
    if (tid < 32) {
        uint32_t c = lcnt[tid];
        if (c > CAP_LDS) c = CAP_LDS;
        lcnt[tid] = c;
        lbase[tid] = atomicAdd(&ws[WS_EQC + b * 32 + tid], c);
    }
    __syncthreads();
    for (int f = 0; f < 32; ++f) {
        const uint32_t c = lcnt[f], base = lbase[f];
        const size_t cb = (size_t)(b * 32 + f) * CAP_COL;
        for (uint32_t i = tid; i < c; i += 256) {
            uint32_t pos = base + i;
            if (pos < CAP_COL) __builtin_nontemporal_store(lbuf[f][i], &gcand[cb + pos]);
        }
    }
}

// ---- 4) per-column exact threshold: 12-bit global digit + compact + LDS radix ----
__global__ __launch_bounds__(256) void kthresh(uint32_t* __restrict__ ws) {
    __shared__ uint32_t lh[4096];      // 16 KB: 12-bit hist / reused 256-bin hists
    __shared__ uint64_t buf[4096];     // 32 KB: compacted survivors
    __shared__ uint32_t cs[256];
    __shared__ uint32_t sh_bin, sh_rr, sh_cnt;
    const int col = blockIdx.x;
    const int tid = threadIdx.x;
    uint32_t cnt = ws[WS_EQC + col];
    if (cnt > CAP_COL) cnt = CAP_COL;
    uint32_t rr = ws[WS_REM + col];
    if (rr > cnt) rr = cnt;
    if (rr == 0) rr = 1;
    const uint64_t* cand = (const uint64_t*)(ws + WS_CAND) + (size_t)col * CAP_COL;

    // --- phase A: global sweep 1 — hist on bits 63:52 ---
    for (int i = tid; i < 4096; i += 256) lh[i] = 0;
    __syncthreads();
    for (uint32_t i = tid; i < cnt; i += 256)
        atomicAdd(&lh[(uint32_t)(cand[i] >> 52)], 1u);
    __syncthreads();
    // hierarchical suffix scan over 4096 bins (16 per thread)
    const int c0 = tid * 16;
    {
        uint32_t run = 0;
        for (int i = 15; i >= 0; --i) { run += lh[c0 + i]; lh[c0 + i] = run; }
        cs[tid] = run;
    }
    __syncthreads();
    for (int off = 1; off < 256; off <<= 1) {
        uint32_t t = (tid + off < 256) ? cs[tid + off] : 0;
        __syncthreads();
        cs[tid] += t;
        __syncthreads();
    }
    {
        uint32_t E = (tid < 255) ? cs[tid + 1] : 0;   // sum of chunks after mine
        for (int i = 0; i < 16; ++i) {
            uint32_t S  = lh[c0 + i] + E;
            uint32_t Sn = ((i < 15) ? lh[c0 + i + 1] : 0u) + E;
            if (S >= rr && Sn < rr) { sh_bin = (uint32_t)(c0 + i); sh_rr = rr - Sn; }
        }
    }
    __syncthreads();
    uint64_t prefix = sh_bin;
    rr = sh_rr;
    int shift = 52;
    __syncthreads();

    // --- phase B: global sweep 2 — compact survivors (deepen in the rare overflow case) ---
    uint32_t lcnt;
    while (true) {
        if (tid == 0) sh_cnt = 0;
        __syncthreads();
        for (uint32_t i = tid; i < cnt; i += 256) {
            uint64_t v = cand[i];
            if ((v >> shift) == prefix) {
                uint32_t idx = atomicAdd(&sh_cnt, 1u);
                if (idx < 4096u) buf[idx] = v;
            }
        }
        __syncthreads();
        if (sh_cnt <= 4096u) { lcnt = sh_cnt; break; }
        // deepen by 8 bits via global hist (practically never taken)
        if (tid < 256) lh[tid] = 0;
        __syncthreads();
        for (uint32_t i = tid; i < cnt; i += 256) {
            uint64_t v = cand[i];
            if ((v >> shift) == prefix)
                atomicAdd(&lh[(uint32_t)(v >> (shift - 8)) & 255u], 1u);
        }
        __syncthreads();
        for (int off = 1; off < 256; off <<= 1) {
            uint32_t t = (tid + off < 256) ? lh[tid + off] : 0;
            __syncthreads();
            lh[tid] += t;
            __syncthreads();
        }
        {
            uint32_t Sb = lh[tid];
            uint32_t Sb1 = (tid < 255) ? lh[tid + 1] : 0;
            if (Sb >= rr && Sb1 < rr) { sh_bin = (uint32_t)tid; sh_rr = rr - Sb1; }
        }
        __syncthreads();
        prefix = (prefix << 8) | sh_bin;
        rr = sh_rr;
        shift -= 8;
        __syncthreads();
    }

    // --- phase C: LDS radix on remaining bits ---
    while (shift > 0) {
        const int w = (shift >= 8) ? 8 : shift;
        lh[tid] = 0;
        __syncthreads();
        for (uint32_t i = tid; i < lcnt; i += 256) {
            uint64_t v = buf[i];
            if ((v >> shift) == prefix)
                atomicAdd(&lh[(uint32_t)(v >> (shift - w)) & ((1u << w) - 1u)], 1u);
        }
        __syncthreads();
        for (int off = 1; off < 256; off <<= 1) {
            uint32_t t = (tid + off < 256) ? lh[tid + off] : 0;
            __syncthreads();
            lh[tid] += t;
            __syncthreads();
        }
        {
            uint32_t Sb = lh[tid];
            uint32_t Sb1 = (tid < 255) ? lh[tid + 1] : 0;
            if (Sb >= rr && Sb1 < rr) { sh_bin = (uint32_t)tid; sh_rr = rr - Sb1; }
        }
        __syncthreads();
        prefix = (prefix << w) | sh_bin;
        rr = sh_rr;
        shift -= w;
        __syncthreads();
    }
    if (tid == 0) ((uint64_t*)(ws + WS_T))[col] = prefix;
}

// ---- 5) mark: exact selection per element; coalesced NT output writes ----
__global__ __launch_bounds__(256) void kmark(const float* __restrict__ xf, const float* __restrict__ mask,
                                             uint32_t* __restrict__ ws, float* __restrict__ upd,
                                             float* __restrict__ omask) {
    __shared__ uint32_t lp[32];
    __shared__ uint64_t lT[32];
    __shared__ float lmin;
    const int b = blockIdx.x >> 7;
    const int blk = blockIdx.x & 127;
    const int tid = threadIdx.x;
    if (tid < 32) {
        lp[tid] = ws[WS_PREF + b * 32 + tid];
        lT[tid] = ((const uint64_t*)(ws + WS_T))[b * 32 + tid];
    }
    if (tid == 0) lmin = __uint_as_float(ws[WS_MIN]);
    __syncthreads();
    const float4* x4 = (const float4*)xf + (size_t)b * 524288;
    f4v* o4 = (f4v*)omask + (size_t)b * 524288;
    const float mn = lmin;
    const int lane = tid & 63;
#pragma unroll
    for (int c = 0; c < 2; ++c) {
        float4 v[8];
#pragma unroll
        for (int k = 0; k < 8; ++k) v[k] = x4[blk * 4096 + c * 2048 + k * 256 + tid];
#pragma unroll
        for (int k = 0; k < 8; ++k) {
            const int e = blk * 4096 + c * 2048 + k * 256 + tid;
            const int n = e >> 3;
            const int fb = (e & 7) * 4;
            float vv[4] = {v[k].x, v[k].y, v[k].z, v[k].w};
            bool sel = false;
#pragma unroll
            for (int j = 0; j < 4; ++j) {
                uint32_t key = fkey(vv[j]);
                uint32_t k9 = key >> 23;
                uint32_t p = lp[fb + j];
                if (k9 > p) {
                    sel = true;
                } else if (k9 == p) {
                    float mk = mask[(size_t)b * NN + n];
                    float sv = ((vv[j] + mn) + EPSF) * mk;
                    uint64_t kk = ((uint64_t)fkey(sv) << 32) | (uint32_t)(~(uint32_t)n);
                    if (kk >= lT[fb + j]) sel = true;
                }
            }
            unsigned long long bal = __ballot(sel);
            uint32_t grp = (uint32_t)(bal >> (lane & 56)) & 0xFFu;
            float u1 = grp ? 1.0f : 0.0f;
            f4v o;
            o.x = vv[0] * u1; o.y = vv[1] * u1; o.z = vv[2] * u1; o.w = vv[3] * u1;
            __builtin_nontemporal_store(o, &o4[e]);
            if ((tid & 7) == 0) __builtin_nontemporal_store(u1, &upd[(size_t)b * NN + n]);
        }
    }
}

extern "C" void kernel_launch(void* const* d_in, const int* in_sizes, int n_in,
                              void* d_out, int out_size, void* d_ws, size_t ws_size,
                              hipStream_t stream) {
    const float* x = (const float*)d_in[0];
    const float* mask = (const float*)d_in[1];
    float* upd = (float*)d_out;                       // (B,N,1)
    float* omask = (float*)d_out + (size_t)BB * NN;   // (B,N,F)
    uint32_t* ws = (uint32_t*)d_ws;

    hipMemsetAsync((char*)d_ws + (size_t)WS_MIN * 4, 0xFF, 4, stream);

    khist<<<BB * SEGH, 512, 0, stream>>>(x, ws);
    kresolve<<<512, 512, 0, stream>>>(ws);            // fused reduce+resolve (+EQC zero)
    kcollect<<<BB * 128, 256, 0, stream>>>(x, mask, ws);
    kthresh<<<512, 256, 0, stream>>>(ws);
    kmark<<<BB * 128, 256, 0, stream>>>(x, mask, ws, upd, omask);
}

// Round 9
// 182.890 us; speedup vs baseline: 2.9096x; 1.0889x over previous
//
#include <hip/hip_runtime.h>
#include <stdint.h>

#define BB   16
#define NN   65536
#define FF   32
#define KSEL 16384
#define EPSF 1e-10f
#define NBIN 512                 // 9-bit first radix: sign + 8 exp bits
#define SEGH 32                  // khist segments per batch
#define CAP_COL 11264            // candidates per column
#define CAP_LDS 128              // LDS staged candidates per feature per block
#define CAP_U   2048             // unsure rows per batch (expected ~140)

typedef float f4v __attribute__((ext_vector_type(4)));

// ---- workspace layout (uint32 element offsets), ~50.5 MB ----
#define WS_MIN    0                          // 1 word (memset 0xFF)
#define WS_PREF   8                          // [512]
#define WS_REM    520                        // [512]
#define WS_T      1032                       // u64[512] (byte 4128, 8-aligned)
#define WS_EQC    2056                       // [512] candidate counters (zeroed in kresolve)
#define WS_UCNT   2568                       // [16] unsure-row counters (zeroed in kresolve)
#define WS_NLIST  2584                       // [16][CAP_U] row indices
#define WS_ULIST  35352                      // [16][CAP_U][32] f32 rows (byte 141408, 16-aligned)
#define WS_CAND   1083928                    // u64[512][CAP_COL] (byte 4335712, 8-aligned)
#define WS_PART   WS_CAND                    // [512][SEGH][NBIN] u32 partials alias cand

__device__ __forceinline__ uint32_t fkey(float s) {
    uint32_t u = __float_as_uint(s);
    return (u & 0x80000000u) ? ~u : (u | 0x80000000u);
}

// ---- 1) fused min(|x|) + 9-bit hist; LDS hist -> NT partial writes [col][s][bin] ----
__global__ __launch_bounds__(512) void khist(const float* __restrict__ xf, uint32_t* __restrict__ ws) {
    __shared__ uint32_t lh[NBIN * 33];
    __shared__ uint32_t rmin[512];
    const int b = blockIdx.x >> 5;
    const int s = blockIdx.x & 31;
    const int tid = threadIdx.x;
    for (int i = tid; i < NBIN * 33; i += 512) lh[i] = 0;
    __syncthreads();
    const float4* x4 = (const float4*)xf + (size_t)b * (NN * FF / 4) + (size_t)s * 16384;
    uint32_t mreg = 0xFFFFFFFFu;
#pragma unroll
    for (int c = 0; c < 4; ++c) {
        float4 v[8];
#pragma unroll
        for (int k = 0; k < 8; ++k) v[k] = x4[c * 4096 + k * 512 + tid];
#pragma unroll
        for (int k = 0; k < 8; ++k) {
            const int e = c * 4096 + k * 512 + tid;
            const int fb = (e & 7) * 4;
            float vv[4] = {v[k].x, v[k].y, v[k].z, v[k].w};
#pragma unroll
            for (int j = 0; j < 4; ++j) {
                uint32_t u = __float_as_uint(vv[j]);
                uint32_t a = u & 0x7FFFFFFFu;
                mreg = a < mreg ? a : mreg;
                uint32_t key = (u & 0x80000000u) ? ~u : (u | 0x80000000u);
                atomicAdd(&lh[(key >> 23) * 33 + fb + j], 1u);
            }
        }
    }
    rmin[tid] = mreg;
    __syncthreads();
    for (int off = 256; off > 0; off >>= 1) {
        if (tid < off) { uint32_t o = rmin[tid + off]; if (o < rmin[tid]) rmin[tid] = o; }
        __syncthreads();
    }
    if (tid == 0) atomicMin(&ws[WS_MIN], rmin[0]);
    uint32_t* part = ws + WS_PART;
    for (int k = tid; k < NBIN * 32; k += 512) {
        const int f = k >> 9, bin = k & 511;
        __builtin_nontemporal_store(lh[bin * 33 + f],
            &part[((size_t)(b * 32 + f) * SEGH + s) * NBIN + bin]);
    }
}

// ---- 2) fused reduce+resolve; also zeroes EQC and UCNT ----
__global__ __launch_bounds__(512) void kresolve(uint32_t* __restrict__ ws) {
    __shared__ uint32_t h[512];
    const int col = blockIdx.x;
    const int bin = threadIdx.x;
    const uint32_t* part = ws + WS_PART;
    uint32_t sum = 0;
#pragma unroll 8
    for (int s = 0; s < SEGH; ++s)
        sum += part[((size_t)col * SEGH + s) * NBIN + bin];
    h[bin] = sum;
    __syncthreads();
    for (int off = 1; off < 512; off <<= 1) {
        uint32_t t = (bin + off < 512) ? h[bin + off] : 0;
        __syncthreads();
        h[bin] += t;
        __syncthreads();
    }
    uint32_t Sb = h[bin];
    uint32_t Sb1 = (bin < 511) ? h[bin + 1] : 0;
    if (Sb >= (uint32_t)KSEL && Sb1 < (uint32_t)KSEL) {
        ws[WS_PREF + col] = (uint32_t)bin;
        ws[WS_REM + col] = (uint32_t)KSEL - Sb1;
    }
    if (bin == 0) ws[WS_EQC + col] = 0;
    if (bin == 1 && col < 16) ws[WS_UCNT + col] = 0;
}

// ---- 3) fused collect + mark: candidates, sure/out rows written, unsure rows deferred ----
__global__ __launch_bounds__(256) void kcmark(const float* __restrict__ xf, const float* __restrict__ mask,
                                              uint32_t* __restrict__ ws, float* __restrict__ upd,
                                              float* __restrict__ omask) {
    __shared__ uint64_t lbuf[32][CAP_LDS];
    __shared__ uint32_t lcnt[32], lbase[32], lp[32];
    __shared__ float lmin;
    const int b = blockIdx.x >> 7;
    const int blk = blockIdx.x & 127;
    const int tid = threadIdx.x;
    if (tid < 32) { lp[tid] = ws[WS_PREF + b * 32 + tid]; lcnt[tid] = 0; }
    if (tid == 0) lmin = __uint_as_float(ws[WS_MIN]);
    __syncthreads();
    const float4* x4 = (const float4*)xf + (size_t)b * 524288;
    f4v* o4 = (f4v*)omask + (size_t)b * 524288;
    const float mn = lmin;
    const int lane = tid & 63;
    uint64_t* gcand = (uint64_t*)(ws + WS_CAND);
    float* ulist = (float*)(ws + WS_ULIST);
#pragma unroll
    for (int c = 0; c < 2; ++c) {
        float4 v[8];
#pragma unroll
        for (int k = 0; k < 8; ++k) v[k] = x4[blk * 4096 + c * 2048 + k * 256 + tid];
#pragma unroll
        for (int k = 0; k < 8; ++k) {
            const int e = blk * 4096 + c * 2048 + k * 256 + tid;
            const int n = e >> 3;
            const int fb = (e & 7) * 4;
            float vv[4] = {v[k].x, v[k].y, v[k].z, v[k].w};
            bool sure = false, bnd = false;
#pragma unroll
            for (int j = 0; j < 4; ++j) {
                uint32_t key = fkey(vv[j]);
                uint32_t k9 = key >> 23;
                uint32_t p = lp[fb + j];
                if (k9 > p) sure = true;
                if (k9 == p) {
                    bnd = true;
                    float mk = mask[(size_t)b * NN + n];
                    float sv = ((vv[j] + mn) + EPSF) * mk;
                    uint64_t v64 = ((uint64_t)fkey(sv) << 32) | (uint32_t)(~(uint32_t)n);
                    const int f = fb + j;
                    uint32_t idx = atomicAdd(&lcnt[f], 1u);
                    if (idx < CAP_LDS) {
                        lbuf[f][idx] = v64;
                    } else {
                        uint32_t col = (uint32_t)(b * 32 + f);
                        uint32_t pos = atomicAdd(&ws[WS_EQC + col], 1u);
                        if (pos < CAP_COL)
                            __builtin_nontemporal_store(v64, &gcand[(size_t)col * CAP_COL + pos]);
                    }
                }
            }
            unsigned long long balS = __ballot(sure);
            unsigned long long balB = __ballot(bnd);
            uint32_t grpS = (uint32_t)(balS >> (lane & 56)) & 0xFFu;
            uint32_t grpB = (uint32_t)(balB >> (lane & 56)) & 0xFFu;
            if (grpS) {                                // sure-selected row
                f4v o; o.x = vv[0]; o.y = vv[1]; o.z = vv[2]; o.w = vv[3];
                __builtin_nontemporal_store(o, &o4[e]);
                if ((tid & 7) == 0) __builtin_nontemporal_store(1.0f, &upd[(size_t)b * NN + n]);
            } else if (!grpB) {                        // fully-out row
                f4v o; o.x = 0.0f; o.y = 0.0f; o.z = 0.0f; o.w = 0.0f;
                __builtin_nontemporal_store(o, &o4[e]);
                if ((tid & 7) == 0) __builtin_nontemporal_store(0.0f, &upd[(size_t)b * NN + n]);
            } else {                                   // unsure: defer to kfix2
                uint32_t slot = 0xFFFFFFFFu;
                if ((tid & 7) == 0) slot = atomicAdd(&ws[WS_UCNT + b], 1u);
                slot = __shfl(slot, (lane & 56));
                if (slot < CAP_U) {
                    float* urow = ulist + ((size_t)(b * CAP_U + slot)) * 32 + (tid & 7) * 4;
                    f4v o; o.x = vv[0]; o.y = vv[1]; o.z = vv[2]; o.w = vv[3];
                    *(f4v*)urow = o;
                    if ((tid & 7) == 0) ws[WS_NLIST + b * CAP_U + slot] = (uint32_t)n;
                }
            }
        }
    }
    __syncthreads();
    if (tid < 32) {
        uint32_t c = lcnt[tid];
        if (c > CAP_LDS) c = CAP_LDS;
        lcnt[tid] = c;
        lbase[tid] = atomicAdd(&ws[WS_EQC + b * 32 + tid], c);
    }
    __syncthreads();
    for (int f = 0; f < 32; ++f) {
        const uint32_t c = lcnt[f], base = lbase[f];
        const size_t cb = (size_t)(b * 32 + f) * CAP_COL;
        for (uint32_t i = tid; i < c; i += 256) {
            uint32_t pos = base + i;
            if (pos < CAP_COL) __builtin_nontemporal_store(lbuf[f][i], &gcand[cb + pos]);
        }
    }
}

// ---- 4) per-column exact threshold: 12-bit global digit + compact + LDS radix ----
__global__ __launch_bounds__(256) void kthresh(uint32_t* __restrict__ ws) {
    __shared__ uint32_t lh[4096];
    __shared__ uint64_t buf[4096];
    __shared__ uint32_t cs[256];
    __shared__ uint32_t sh_bin, sh_rr, sh_cnt;
    const int col = blockIdx.x;
    const int tid = threadIdx.x;
    uint32_t cnt = ws[WS_EQC + col];
    if (cnt > CAP_COL) cnt = CAP_COL;
    uint32_t rr = ws[WS_REM + col];
    if (rr > cnt) rr = cnt;
    if (rr == 0) rr = 1;
    const uint64_t* cand = (const uint64_t*)(ws + WS_CAND) + (size_t)col * CAP_COL;

    for (int i = tid; i < 4096; i += 256) lh[i] = 0;
    __syncthreads();
    for (uint32_t i = tid; i < cnt; i += 256)
        atomicAdd(&lh[(uint32_t)(cand[i] >> 52)], 1u);
    __syncthreads();
    const int c0 = tid * 16;
    {
        uint32_t run = 0;
        for (int i = 15; i >= 0; --i) { run += lh[c0 + i]; lh[c0 + i] = run; }
        cs[tid] = run;
    }
    __syncthreads();
    for (int off = 1; off < 256; off <<= 1) {
        uint32_t t = (tid + off < 256) ? cs[tid + off] : 0;
        __syncthreads();
        cs[tid] += t;
        __syncthreads();
    }
    {
        uint32_t E = (tid < 255) ? cs[tid + 1] : 0;
        for (int i = 0; i < 16; ++i) {
            uint32_t S  = lh[c0 + i] + E;
            uint32_t Sn = ((i < 15) ? lh[c0 + i + 1] : 0u) + E;
            if (S >= rr && Sn < rr) { sh_bin = (uint32_t)(c0 + i); sh_rr = rr - Sn; }
        }
    }
    __syncthreads();
    uint64_t prefix = sh_bin;
    rr = sh_rr;
    int shift = 52;
    __syncthreads();

    uint32_t lcnt;
    while (true) {
        if (tid == 0) sh_cnt = 0;
        __syncthreads();
        for (uint32_t i = tid; i < cnt; i += 256) {
            uint64_t v = cand[i];
            if ((v >> shift) == prefix) {
                uint32_t idx = atomicAdd(&sh_cnt, 1u);
                if (idx < 4096u) buf[idx] = v;
            }
        }
        __syncthreads();
        if (sh_cnt <= 4096u) { lcnt = sh_cnt; break; }
        if (tid < 256) lh[tid] = 0;
        __syncthreads();
        for (uint32_t i = tid; i < cnt; i += 256) {
            uint64_t v = cand[i];
            if ((v >> shift) == prefix)
                atomicAdd(&lh[(uint32_t)(v >> (shift - 8)) & 255u], 1u);
        }
        __syncthreads();
        for (int off = 1; off < 256; off <<= 1) {
            uint32_t t = (tid + off < 256) ? lh[tid + off] : 0;
            __syncthreads();
            lh[tid] += t;
            __syncthreads();
        }
        {
            uint32_t Sb = lh[tid];
            uint32_t Sb1 = (tid < 255) ? lh[tid + 1] : 0;
            if (Sb >= rr && Sb1 < rr) { sh_bin = (uint32_t)tid; sh_rr = rr - Sb1; }
        }
        __syncthreads();
        prefix = (prefix << 8) | sh_bin;
        rr = sh_rr;
        shift -= 8;
        __syncthreads();
    }

    while (shift > 0) {
        const int w = (shift >= 8) ? 8 : shift;
        lh[tid] = 0;
        __syncthreads();
        for (uint32_t i = tid; i < lcnt; i += 256) {
            uint64_t v = buf[i];
            if ((v >> shift) == prefix)
                atomicAdd(&lh[(uint32_t)(v >> (shift - w)) & ((1u << w) - 1u)], 1u);
        }
        __syncthreads();
        for (int off = 1; off < 256; off <<= 1) {
            uint32_t t = (tid + off < 256) ? lh[tid + off] : 0;
            __syncthreads();
            lh[tid] += t;
            __syncthreads();
        }
        {
            uint32_t Sb = lh[tid];
            uint32_t Sb1 = (tid < 255) ? lh[tid + 1] : 0;
            if (Sb >= rr && Sb1 < rr) { sh_bin = (uint32_t)tid; sh_rr = rr - Sb1; }
        }
        __syncthreads();
        prefix = (prefix << w) | sh_bin;
        rr = sh_rr;
        shift -= w;
        __syncthreads();
    }
    if (tid == 0) ((uint64_t*)(ws + WS_T))[col] = prefix;
}

// ---- 5) fallback full mark: no-op unless a batch overflowed CAP_U ----
__global__ __launch_bounds__(256) void kmark_full(const float* __restrict__ xf, const float* __restrict__ mask,
                                                  uint32_t* __restrict__ ws, float* __restrict__ upd,
                                                  float* __restrict__ omask) {
    const int b = blockIdx.x >> 7;
    if (ws[WS_UCNT + b] <= CAP_U) return;
    __shared__ uint32_t lp[32];
    __shared__ uint64_t lT[32];
    __shared__ float lmin;
    const int blk = blockIdx.x & 127;
    const int tid = threadIdx.x;
    if (tid < 32) {
        lp[tid] = ws[WS_PREF + b * 32 + tid];
        lT[tid] = ((const uint64_t*)(ws + WS_T))[b * 32 + tid];
    }
    if (tid == 0) lmin = __uint_as_float(ws[WS_MIN]);
    __syncthreads();
    const float4* x4 = (const float4*)xf + (size_t)b * 524288;
    f4v* o4 = (f4v*)omask + (size_t)b * 524288;
    const float mn = lmin;
    const int lane = tid & 63;
#pragma unroll
    for (int c = 0; c < 2; ++c) {
        float4 v[8];
#pragma unroll
        for (int k = 0; k < 8; ++k) v[k] = x4[blk * 4096 + c * 2048 + k * 256 + tid];
#pragma unroll
        for (int k = 0; k < 8; ++k) {
            const int e = blk * 4096 + c * 2048 + k * 256 + tid;
            const int n = e >> 3;
            const int fb = (e & 7) * 4;
            float vv[4] = {v[k].x, v[k].y, v[k].z, v[k].w};
            bool sel = false;
#pragma unroll
            for (int j = 0; j < 4; ++j) {
                uint32_t key = fkey(vv[j]);
                uint32_t k9 = key >> 23;
                uint32_t p = lp[fb + j];
                if (k9 > p) sel = true;
                else if (k9 == p) {
                    float mk = mask[(size_t)b * NN + n];
                    float sv = ((vv[j] + mn) + EPSF) * mk;
                    uint64_t kk = ((uint64_t)fkey(sv) << 32) | (uint32_t)(~(uint32_t)n);
                    if (kk >= lT[fb + j]) sel = true;
                }
            }
            unsigned long long bal = __ballot(sel);
            uint32_t grp = (uint32_t)(bal >> (lane & 56)) & 0xFFu;
            float u1 = grp ? 1.0f : 0.0f;
            f4v o;
            o.x = vv[0] * u1; o.y = vv[1] * u1; o.z = vv[2] * u1; o.w = vv[3] * u1;
            __builtin_nontemporal_store(o, &o4[e]);
            if ((tid & 7) == 0) __builtin_nontemporal_store(u1, &upd[(size_t)b * NN + n]);
        }
    }
}

// ---- 6) finish unsure rows exactly (reads stored rows, ~140/batch) ----
__global__ __launch_bounds__(256) void kfix2(const float* __restrict__ mask, uint32_t* __restrict__ ws,
                                             float* __restrict__ upd, float* __restrict__ omask) {
    __shared__ uint32_t lp[32];
    __shared__ uint64_t lT[32];
    __shared__ float lmin;
    const int b = blockIdx.x;
    const int tid = threadIdx.x;
    if (tid < 32) {
        lp[tid] = ws[WS_PREF + b * 32 + tid];
        lT[tid] = ((const uint64_t*)(ws + WS_T))[b * 32 + tid];
    }
    if (tid == 0) lmin = __uint_as_float(ws[WS_MIN]);
    __syncthreads();
    uint32_t cnt = ws[WS_UCNT + b];
    if (cnt > CAP_U) cnt = CAP_U;
    const float mn = lmin;
    const int lane = tid & 63;
    const float* ulist = (const float*)(ws + WS_ULIST);
    f4v* o4 = (f4v*)omask + (size_t)b * 524288;
    for (uint32_t r0 = 0; r0 < cnt; r0 += 32) {
        uint32_t r = r0 + (tid >> 3);
        bool act = r < cnt;
        uint32_t n = 0;
        f4v vx = {0, 0, 0, 0};
        bool sel = false;
        if (act) {
            n = ws[WS_NLIST + b * CAP_U + r];
            vx = *(const f4v*)(ulist + ((size_t)(b * CAP_U + r)) * 32 + (tid & 7) * 4);
            float mk = mask[(size_t)b * NN + n];
            const int fb = (tid & 7) * 4;
            float vv[4] = {vx.x, vx.y, vx.z, vx.w};
#pragma unroll
            for (int j = 0; j < 4; ++j) {
                uint32_t key = fkey(vv[j]);
                uint32_t k9 = key >> 23;
                uint32_t p = lp[fb + j];
                if (k9 > p) sel = true;
                else if (k9 == p) {
                    float sv = ((vv[j] + mn) + EPSF) * mk;
                    uint64_t kk = ((uint64_t)fkey(sv) << 32) | (uint32_t)(~(uint32_t)n);
                    if (kk >= lT[fb + j]) sel = true;
                }
            }
        }
        unsigned long long bal = __ballot(sel);
        uint32_t grp = (uint32_t)(bal >> (lane & 56)) & 0xFFu;
        if (act) {
            float u1 = grp ? 1.0f : 0.0f;
            f4v o;
            o.x = vx.x * u1; o.y = vx.y * u1; o.z = vx.z * u1; o.w = vx.w * u1;
            o4[(size_t)n * 8 + (tid & 7)] = o;
            if ((tid & 7) == 0) upd[(size_t)b * NN + n] = u1;
        }
    }
}

extern "C" void kernel_launch(void* const* d_in, const int* in_sizes, int n_in,
                              void* d_out, int out_size, void* d_ws, size_t ws_size,
                              hipStream_t stream) {
    const float* x = (const float*)d_in[0];
    const float* mask = (const float*)d_in[1];
    float* upd = (float*)d_out;                       // (B,N,1)
    float* omask = (float*)d_out + (size_t)BB * NN;   // (B,N,F)
    uint32_t* ws = (uint32_t*)d_ws;

    hipMemsetAsync((char*)d_ws + (size_t)WS_MIN * 4, 0xFF, 4, stream);

    khist<<<BB * SEGH, 512, 0, stream>>>(x, ws);
    kresolve<<<512, 512, 0, stream>>>(ws);
    kcmark<<<BB * 128, 256, 0, stream>>>(x, mask, ws, upd, omask);
    kthresh<<<512, 256, 0, stream>>>(ws);
    kmark_full<<<BB * 128, 256, 0, stream>>>(x, mask, ws, upd, omask);
    kfix2<<<BB, 256, 0, stream>>>(mask, ws, upd, omask);
}